// Round 1
// baseline (1054.619 us; speedup 1.0000x reference)
//
#include <hip/hip_runtime.h>

#define DEV __device__ __forceinline__

DEV unsigned enc_max(float f) {
  unsigned u = __float_as_uint(f);
  return (u & 0x80000000u) ? ~u : (u | 0x80000000u);
}
DEV float dec_max(unsigned u) {
  unsigned v = (u & 0x80000000u) ? (u & 0x7fffffffu) : ~u;
  return __uint_as_float(v);
}

DEV float mask_val(const unsigned char* mb, int n) {
  // Detect train_mask storage from its first element: uint8 bool / int32 / float32.
  unsigned b0 = mb[0], b1 = mb[1], b2 = mb[2], b3 = mb[3];
  if (b0 <= 1u && b1 == b0 && b2 == b0 && b3 == b0) {
    return mb[n] ? 1.f : 0.f;                       // 1-byte bool
  } else if (b1 == 0u && b2 == 0u && b3 == 0u) {
    return ((const int*)mb)[n] ? 1.f : 0.f;         // int32
  } else {
    return (((const float*)mb)[n] != 0.f) ? 1.f : 0.f; // float32
  }
}

// ---------------- K0: rank-1 collapses of the context-attention algebra ----------------
// enc_proj0[c] = tanh(ti*A0[c] + B0[c]); enc_proj1[c] = tanh(dg*A1[c] + B1[c])
// sum_j context[j]*comb_w[64+j][c] = s0*(ti*P0[c]+Q0[c]) + s1*(dg*P1[c]+Q1[c])
__global__ void k_precompute(const float* __restrict__ tf_w, const float* __restrict__ tf_b,
                             const float* __restrict__ deg_w, const float* __restrict__ deg_b,
                             const float* __restrict__ wenc_w, const float* __restrict__ wenc_b,
                             const float* __restrict__ comb_w, float* __restrict__ cbuf) {
  int c = threadIdx.x;  // 64 threads
  float A0 = 0, B0 = 0, A1 = 0, B1 = 0, P0 = 0, Q0 = 0, P1 = 0, Q1 = 0;
  for (int j = 0; j < 64; ++j) {
    float w  = wenc_w[j * 64 + c];
    float cw = comb_w[(64 + j) * 64 + c];
    float twj = tf_w[j], tbj = tf_b[j], dwj = deg_w[j], dbj = deg_b[j];
    A0 += twj * w;  B0 += tbj * w;
    A1 += dwj * w;  B1 += dbj * w;
    P0 += twj * cw; Q0 += tbj * cw;
    P1 += dwj * cw; Q1 += dbj * cw;
  }
  float wb = wenc_b[c];
  cbuf[c]       = A0; cbuf[64 + c]  = B0 + wb;
  cbuf[128 + c] = A1; cbuf[192 + c] = B1 + wb;
  cbuf[256 + c] = P0; cbuf[320 + c] = Q0;
  cbuf[384 + c] = P1; cbuf[448 + c] = Q1;
}

// ---------------- K1: h = relu(x@lin); q,k,v,skip = h@W + b ----------------
// lane = output channel; weight column register-cached; x/h rows broadcast-float4 from LDS.
DEV float dot64_bcast(const float4* __restrict__ row, const float* __restrict__ w, float acc) {
#pragma unroll
  for (int j4 = 0; j4 < 16; ++j4) {
    float4 hv = row[j4];
    acc = fmaf(hv.x, w[4 * j4 + 0], acc);
    acc = fmaf(hv.y, w[4 * j4 + 1], acc);
    acc = fmaf(hv.z, w[4 * j4 + 2], acc);
    acc = fmaf(hv.w, w[4 * j4 + 3], acc);
  }
  return acc;
}

__global__ __launch_bounds__(256) void k_node_proj(
    const float* __restrict__ x,
    const float* __restrict__ lin_w, const float* __restrict__ lin_b,
    const float* __restrict__ Wq, const float* __restrict__ bq,
    const float* __restrict__ Wk, const float* __restrict__ bk,
    const float* __restrict__ Wv, const float* __restrict__ bv,
    const float* __restrict__ Wsk, const float* __restrict__ bsk,
    float* __restrict__ q, float* __restrict__ k, float* __restrict__ v,
    float* __restrict__ skipout, int N) {
  __shared__ float xs[4096];
  __shared__ float hs[4096];
  const int tid = threadIdx.x;
  const int c = tid & 63;
  const int rr0 = tid >> 6;
  const int ntiles = (N + 63) >> 6;
  for (int tile = blockIdx.x; tile < ntiles; tile += gridDim.x) {
    const int base = tile << 6;
    for (int idx = tid; idx < 4096; idx += 256) {
      int n = base + (idx >> 6);
      xs[idx] = (n < N) ? x[(size_t)n * 64 + (idx & 63)] : 0.f;
    }
    __syncthreads();
    {
      float w[64];
#pragma unroll
      for (int j = 0; j < 64; ++j) w[j] = lin_w[j * 64 + c];
      const float bias = lin_b[c];
      for (int r = rr0; r < 64; r += 4) {
        float acc = dot64_bcast((const float4*)&xs[r << 6], w, bias);
        hs[(r << 6) + c] = fmaxf(acc, 0.f);
      }
    }
    __syncthreads();
    const float* Wm[4] = {Wq, Wk, Wv, Wsk};
    const float* bm[4] = {bq, bk, bv, bsk};
    float* om[4] = {q, k, v, skipout};
#pragma unroll
    for (int mm = 0; mm < 4; ++mm) {
      float w[64];
#pragma unroll
      for (int j = 0; j < 64; ++j) w[j] = Wm[mm][j * 64 + c];
      const float bias = bm[mm][c];
      for (int r = rr0; r < 64; r += 4) {
        const int n = base + r;
        float acc = dot64_bcast((const float4*)&hs[r << 6], w, bias);
        if (n < N) om[mm][(size_t)n * 64 + c] = acc;
      }
    }
    __syncthreads();
  }
}

// ---------------- K2: per-edge alpha + segment max (atomicMax, ordered-uint) ----------------
__global__ __launch_bounds__(256) void k_edge_alpha(
    const int* __restrict__ ei,
    const float* __restrict__ node_time, const float* __restrict__ edge_time,
    const float* __restrict__ time_w, const float* __restrict__ time_b,
    const float* __restrict__ We, const float* __restrict__ be,
    const float* __restrict__ q, const float* __restrict__ k,
    float* __restrict__ alpha, unsigned* __restrict__ menc, int E) {
  const int tid = threadIdx.x;
  const int c = tid & 63;
  float wcol[32];
#pragma unroll
  for (int j = 0; j < 32; ++j) wcol[j] = We[j * 64 + c];
  const float bec = be[c];
  const float tw = time_w[c & 31];
  const float tb = time_b[c & 31];
  const int estart = blockIdx.x * 4 + (tid >> 6);
  const int estride = gridDim.x * 4;
  for (int e = estart; e < E; e += estride) {
    const int src = ei[e];
    const int dst = ei[E + e];
    const float rel = node_time[src] - edge_time[e];
    const float rv = cosf(fmaf(rel, tw, tb));  // lanes 32..63 mirror lanes 0..31
    float acc = bec;
#pragma unroll
    for (int j = 0; j < 32; ++j) {
      float rj = __uint_as_float((unsigned)__builtin_amdgcn_readlane((int)__float_as_uint(rv), j));
      acc = fmaf(rj, wcol[j], acc);
    }
    const float ke = k[(size_t)src * 64 + c] + acc;
    const float qd = q[(size_t)dst * 64 + c];
    float p = qd * ke;
#pragma unroll
    for (int m = 16; m >= 1; m >>= 1) p += __shfl_xor(p, m, 64);
    const float al = p * 0.17677669529663687f;  // 1/sqrt(32)
    if ((c & 31) == 0) {
      const int h = c >> 5;
      alpha[(size_t)e * 2 + h] = al;
      atomicMax(&menc[(size_t)dst * 2 + h], enc_max(al));
    }
  }
}

// ---------------- K3: ea = exp(alpha-m); scatter num += ea*v_e, denom += ea ----------------
__global__ __launch_bounds__(256) void k_edge_scatter(
    const int* __restrict__ ei,
    const float* __restrict__ node_time, const float* __restrict__ edge_time,
    const float* __restrict__ time_w, const float* __restrict__ time_b,
    const float* __restrict__ We, const float* __restrict__ be,
    const float* __restrict__ v, const float* __restrict__ alpha,
    const unsigned* __restrict__ menc,
    float* __restrict__ num, float* __restrict__ denom, int E) {
  const int tid = threadIdx.x;
  const int c = tid & 63;
  float wcol[32];
#pragma unroll
  for (int j = 0; j < 32; ++j) wcol[j] = We[j * 64 + c];
  const float bec = be[c];
  const float tw = time_w[c & 31];
  const float tb = time_b[c & 31];
  const int estart = blockIdx.x * 4 + (tid >> 6);
  const int estride = gridDim.x * 4;
  for (int e = estart; e < E; e += estride) {
    const int src = ei[e];
    const int dst = ei[E + e];
    const float rel = node_time[src] - edge_time[e];
    const float rv = cosf(fmaf(rel, tw, tb));
    float acc = bec;
#pragma unroll
    for (int j = 0; j < 32; ++j) {
      float rj = __uint_as_float((unsigned)__builtin_amdgcn_readlane((int)__float_as_uint(rv), j));
      acc = fmaf(rj, wcol[j], acc);
    }
    const float ve = v[(size_t)src * 64 + c] + acc;
    const int h = c >> 5;
    const float al = alpha[(size_t)e * 2 + h];
    const float mv = dec_max(menc[(size_t)dst * 2 + h]);
    const float ea = expf(al - mv);
    atomicAdd(&num[(size_t)dst * 64 + c], ea * ve);
    if ((c & 31) == 0) atomicAdd(&denom[(size_t)dst * 2 + h], ea);
  }
}

// ---------------- K4: epilogue (agg + context attention + combine + out + log_softmax) ----------------
__global__ __launch_bounds__(256) void k_epilogue(
    const float* __restrict__ num, const float* __restrict__ denom,
    const float* __restrict__ t_int, const float* __restrict__ deg,
    const float* __restrict__ cbuf,
    const float* __restrict__ wx_w, const float* __restrict__ wx_b,
    const float* __restrict__ comb_w, const float* __restrict__ comb_b,
    const float* __restrict__ out_w, const float* __restrict__ out_b,
    const int* __restrict__ y, const unsigned char* __restrict__ maskb,
    float* __restrict__ out, int N) {
  __shared__ float sh[4][64];
  const int tid = threadIdx.x;
  const int c = tid & 63;
  const int wv = tid >> 6;
  float wxreg[64], cbreg[64];
#pragma unroll
  for (int j = 0; j < 64; ++j) { wxreg[j] = wx_w[j * 64 + c]; cbreg[j] = comb_w[j * 64 + c]; }
  const float A0 = cbuf[c], B0 = cbuf[64 + c], A1 = cbuf[128 + c], B1 = cbuf[192 + c];
  const float P0 = cbuf[256 + c], Q0 = cbuf[320 + c], P1 = cbuf[384 + c], Q1 = cbuf[448 + c];
  const float wxb = wx_b[c], cbb = comb_b[c];
  const float ow0 = out_w[c * 2 + 0], ow1 = out_w[c * 2 + 1];
  const float ob0 = out_b[0], ob1 = out_b[1];
  const size_t O1 = (size_t)N * 64;
  const size_t O2 = O1 + (size_t)N * 2;
  const size_t O3 = O2 + (size_t)N;
  const int ngroups = (N + 3) >> 2;
  for (int g = blockIdx.x; g < ngroups; g += gridDim.x) {
    const int n = g * 4 + wv;
    const bool act = n < N;
    float h1a = 0.f, ti = 0.f, dg = 0.f;
    if (act) {
      const float dn = denom[(size_t)n * 2 + (c >> 5)];
      // skip connection was staged into out[0:N*64) by K1
      h1a = num[(size_t)n * 64 + c] / (dn + 1e-16f) + out[(size_t)n * 64 + c];
      ti = t_int[n];
      dg = deg[n];
    }
    sh[wv][c] = h1a;
    __syncthreads();
    const float4* hr = (const float4*)&sh[wv][0];
    float xp = wxb;
    float acc = cbb;
#pragma unroll
    for (int j4 = 0; j4 < 16; ++j4) {
      float4 hv = hr[j4];
      xp  = fmaf(hv.x, wxreg[4 * j4 + 0], xp);
      xp  = fmaf(hv.y, wxreg[4 * j4 + 1], xp);
      xp  = fmaf(hv.z, wxreg[4 * j4 + 2], xp);
      xp  = fmaf(hv.w, wxreg[4 * j4 + 3], xp);
      acc = fmaf(hv.x, cbreg[4 * j4 + 0], acc);
      acc = fmaf(hv.y, cbreg[4 * j4 + 1], acc);
      acc = fmaf(hv.z, cbreg[4 * j4 + 2], acc);
      acc = fmaf(hv.w, cbreg[4 * j4 + 3], acc);
    }
    xp = tanhf(xp);
    const float ep0 = tanhf(fmaf(ti, A0, B0));
    const float ep1 = tanhf(fmaf(dg, A1, B1));
    float d0 = ep0 * xp, d1 = ep1 * xp;
#pragma unroll
    for (int m = 32; m >= 1; m >>= 1) { d0 += __shfl_xor(d0, m, 64); d1 += __shfl_xor(d1, m, 64); }
    const float mx = fmaxf(d0, d1);
    const float e0 = expf(d0 - mx), e1 = expf(d1 - mx);
    const float sden = e0 + e1;
    const float s0 = e0 / sden, s1 = e1 / sden;
    acc = fmaf(s0, fmaf(ti, P0, Q0), acc);
    acc = fmaf(s1, fmaf(dg, P1, Q1), acc);
    float z0 = acc * ow0, z1 = acc * ow1;
#pragma unroll
    for (int m = 32; m >= 1; m >>= 1) { z0 += __shfl_xor(z0, m, 64); z1 += __shfl_xor(z1, m, 64); }
    if (act) {
      out[(size_t)n * 64 + c] = acc;  // final h1 overwrites the staged skip
      if (c == 0) {
        z0 += ob0; z1 += ob1;
        const float mz = fmaxf(z0, z1);
        const float lse = mz + logf(expf(z0 - mz) + expf(z1 - mz));
        out[O1 + (size_t)n * 2 + 0] = z0 - lse;
        out[O1 + (size_t)n * 2 + 1] = z1 - lse;
        out[O2 + (size_t)n] = (float)y[n];
        out[O3 + (size_t)n] = mask_val(maskb, n);
      }
    }
    __syncthreads();
  }
}

extern "C" void kernel_launch(void* const* d_in, const int* in_sizes, int n_in,
                              void* d_out, int out_size, void* d_ws, size_t ws_size,
                              hipStream_t stream) {
  const float* x          = (const float*)d_in[0];
  const int*   ei         = (const int*)d_in[1];
  const float* node_time  = (const float*)d_in[2];
  const float* edge_time  = (const float*)d_in[3];
  const float* nmoti      = (const float*)d_in[4];
  const float* nod        = (const float*)d_in[5];
  const int*   y          = (const int*)d_in[6];
  const unsigned char* mask = (const unsigned char*)d_in[7];
  const float* time_w = (const float*)d_in[8];
  const float* time_b = (const float*)d_in[9];
  const float* tf_w   = (const float*)d_in[10];
  const float* tf_b   = (const float*)d_in[11];
  const float* deg_w  = (const float*)d_in[12];
  const float* deg_b  = (const float*)d_in[13];
  const float* lin_w  = (const float*)d_in[14];
  const float* lin_b  = (const float*)d_in[15];
  const float* Wq     = (const float*)d_in[16];
  const float* bq     = (const float*)d_in[17];
  const float* Wk     = (const float*)d_in[18];
  const float* bk     = (const float*)d_in[19];
  const float* Wv     = (const float*)d_in[20];
  const float* bv     = (const float*)d_in[21];
  const float* We     = (const float*)d_in[22];
  const float* be     = (const float*)d_in[23];
  const float* Wsk    = (const float*)d_in[24];
  const float* bsk    = (const float*)d_in[25];
  const float* wenc_w = (const float*)d_in[26];
  const float* wenc_b = (const float*)d_in[27];
  const float* wx_w   = (const float*)d_in[28];
  const float* wx_b   = (const float*)d_in[29];
  const float* comb_w = (const float*)d_in[30];
  const float* comb_b = (const float*)d_in[31];
  const float* out_w  = (const float*)d_in[32];
  const float* out_b  = (const float*)d_in[33];

  const int N = in_sizes[2];   // node_time
  const int E = in_sizes[3];   // edge_time
  const size_t N64 = (size_t)N * 64;

  float*    q     = (float*)d_ws;
  float*    k     = q + N64;
  float*    v     = k + N64;
  float*    num   = v + N64;
  float*    alpha = num + N64;
  unsigned* menc  = (unsigned*)(alpha + (size_t)E * 2);
  float*    denom = (float*)(menc + (size_t)N * 2);
  float*    cbuf  = denom + (size_t)N * 2;
  float*    outf  = (float*)d_out;
  float*    skip  = outf;  // stage skip in d_out[0:N*64); K4 overwrites with final h1

  // per-call scratch re-init (workspace is NOT re-poisoned between replays)
  hipMemsetAsync(num, 0, N64 * sizeof(float), stream);
  hipMemsetAsync(menc, 0, (size_t)N * 4 * sizeof(unsigned), stream);  // menc + denom (contiguous)

  k_precompute<<<1, 64, 0, stream>>>(tf_w, tf_b, deg_w, deg_b, wenc_w, wenc_b, comb_w, cbuf);

  const int ntiles = (N + 63) >> 6;
  k_node_proj<<<ntiles, 256, 0, stream>>>(x, lin_w, lin_b, Wq, bq, Wk, bk, Wv, bv, Wsk, bsk,
                                          q, k, v, skip, N);

  k_edge_alpha<<<2048, 256, 0, stream>>>(ei, node_time, edge_time, time_w, time_b, We, be,
                                         q, k, alpha, menc, E);

  k_edge_scatter<<<2048, 256, 0, stream>>>(ei, node_time, edge_time, time_w, time_b, We, be,
                                           v, alpha, menc, num, denom, E);

  k_epilogue<<<2048, 256, 0, stream>>>(num, denom, nmoti, nod, cbuf, wx_w, wx_b,
                                       comb_w, comb_b, out_w, out_b, y, mask, outf, N);
}